// Round 4
// baseline (244.207 us; speedup 1.0000x reference)
//
#include <hip/hip_runtime.h>
#include <hip/hip_bf16.h>

// LUTLayerBasic: out[b] = sum_d W[d*16 + ch(b,d)], ch = 4 sign bits of gathered x.
// R4: one-hot bf16 MFMA GEMM with T3+T4 counted-vmcnt pipeline.
//  - 4-deep half-tile (K=32) pipeline: 4 LDS buffers, 3 global_load_lds per
//    half per wave (uniform), steady-state s_waitcnt vmcnt(6), raw s_barrier
//    (never vmcnt(0) in the main loop).
//  - A one-hot fragments built arithmetically (verified R3 path), channels
//    staged in LDS pre-transposed so each wave needs one ds_read_b64.
//  - W pre-permuted to MFMA-fragment-linear bf16 (verified R1-R3 path).
//  - Split-K KP=4 via HW f32 atomics into memset-zeroed out.
//
// Dims: B=2048, N_IN=2048, D=1024, A=4, O=2048, C=16, K=N_LUT=16384.

typedef __attribute__((ext_vector_type(8))) short short8;
typedef __attribute__((ext_vector_type(4))) float f32x4;

__device__ __forceinline__ bool anchors_is_i64(const int* a) {
  int v = 0;
#pragma unroll
  for (int i = 0; i < 32; ++i) v |= a[2 * i + 1];
  return v == 0;
}

__device__ __forceinline__ int ld_anchor(const int* a, int i, bool is64) {
  return is64 ? a[2 * i] : a[i];
}

__device__ __forceinline__ unsigned f2bf(float f) {  // RNE f32 -> bf16
  unsigned u = __float_as_uint(f);
  return ((u + 0x7fffu + ((u >> 16) & 1u)) >> 16) & 0xffffu;
}

// ---------------------------------------------------------------------------
// Kernel 1: packed channels, TRANSPOSED for LDS-friendly fragment reads.
// For sample s = g*128 + m8*16 + r (g in [0,16), m8 in [0,8), r in [0,16)) and
// detector-pair t: chT[t*2048 + g*128 + r*8 + m8] = ch(s,2t) | ch(s,2t+1)<<8.
// ---------------------------------------------------------------------------
__global__ __launch_bounds__(256) void k_channels(const float* __restrict__ x,
                                                  const int* __restrict__ anc,
                                                  unsigned short* __restrict__ chT) {
  const int s = blockIdx.x * 256 + threadIdx.x;  // gridDim.x = 8
  const int t = blockIdx.y;                      // [0, 512)
  const bool is64 = anchors_is_i64(anc);
  unsigned ch0 = 0, ch1 = 0;
#pragma unroll
  for (int i = 0; i < 4; ++i) {
    int a0 = ld_anchor(anc, (2 * t) * 4 + i, is64);
    int a1 = ld_anchor(anc, (2 * t + 1) * 4 + i, is64);
    ch0 |= (x[(size_t)s * 2048 + a0] > 0.0f ? 1u : 0u) << i;
    ch1 |= (x[(size_t)s * 2048 + a1] > 0.0f ? 1u : 0u) << i;
  }
  const int g = s >> 7, m8 = (s >> 4) & 7, r = s & 15;
  chT[(size_t)t * 2048 + g * 128 + r * 8 + m8] =
      (unsigned short)(ch0 | (ch1 << 8));
}

// ---------------------------------------------------------------------------
// Kernel 2: W (f32 [16384][2048]) -> bf16 fragment-linear chunks:
//   chunk ((kt*128 + nc)*64 + l) is 16 B holding
//   W[kt*32 + kmap(l>>4, j)][nc*16 + (l&15)], kmap(q,j)=q*4+(j&3)+16*(j>>2).
// ---------------------------------------------------------------------------
__global__ __launch_bounds__(256) void k_wfrag(const float* __restrict__ W,
                                               uint4* __restrict__ wf) {
  const unsigned flat = blockIdx.x * 256 + threadIdx.x;  // [0, 4194304)
  const unsigned l = flat & 63u, nc = (flat >> 6) & 127u, kt = flat >> 13;
  const unsigned q = l >> 4, col = nc * 16 + (l & 15);
  unsigned hs[8];
#pragma unroll
  for (int j = 0; j < 8; ++j) {
    unsigned k = kt * 32 + q * 4 + (j & 3) + ((j >> 2) << 4);
    hs[j] = f2bf(W[(size_t)k * 2048 + col]);
  }
  uint4 o;
  o.x = hs[0] | (hs[1] << 16);
  o.y = hs[2] | (hs[3] << 16);
  o.z = hs[4] | (hs[5] << 16);
  o.w = hs[6] | (hs[7] << 16);
  wf[flat] = o;
}

// ---------------------------------------------------------------------------
// Kernel 3: one-hot GEMM, counted-vmcnt 4-deep pipeline. Tile 128x128,
// 4 waves 2x2, wave 64x64, half = K=32, NH=128 halves, KP=4 via atomics.
// ---------------------------------------------------------------------------
__global__ __launch_bounds__(256, 4) void k_gemm(const uint4* __restrict__ wf,
                                                 const unsigned short* __restrict__ chT,
                                                 float* __restrict__ out) {
  constexpr int NH = 128;          // K-halves per kp slice (512 pairs / KP=4)
  __shared__ uint4 wb[4][512];     // 4 x 8 KiB W half-buffers
  __shared__ unsigned short cb[4][128];  // 4 x 256 B channel half-buffers

  const int tid = threadIdx.x, lane = tid & 63;
  const int w = tid >> 6, wm = w >> 1, wn = w & 1;

  // XCD-grouping swizzle (1024 = 8 XCD x 128): all 16 mBlk's of one (nBlk,kp)
  // W-panel on one XCD -> 2 MiB panel L2-resident.
  const unsigned orig = blockIdx.x;
  const unsigned xcd = orig & 7u, slot = orig >> 3;
  const unsigned pl = slot >> 4, mBlk = slot & 15u;
  const unsigned panel = xcd * 8u + pl;  // [0, 64)
  const unsigned nBlk = panel & 15u, kp = panel >> 4;
  const int kt0 = (int)kp * NH;

  const uint4* wsrc = wf + ((size_t)(unsigned)kt0 * 128u + nBlk * 8u) * 64u;
  const char* csrc = (const char*)(chT + (size_t)(unsigned)kt0 * 2048u + mBlk * 128u) +
                     (unsigned)lane * 4u;

  // Stage half h: 2x W gload16 + 1x ch gload4 (all 4 waves stage ch
  // redundantly -> uniform 3 vmem ops per wave per stage for vmcnt counting).
  auto stage = [&](int h) {
    const int buf = h & 3;
    const uint4* ws = wsrc + (size_t)h * 8192;
#pragma unroll
    for (int t2 = 0; t2 < 2; ++t2) {
      __builtin_amdgcn_global_load_lds(
          (const __attribute__((address_space(1))) void*)(ws + t2 * 256 + tid),
          (__attribute__((address_space(3))) void*)(&wb[buf][t2 * 256 + w * 64]),
          16, 0, 0);
    }
    __builtin_amdgcn_global_load_lds(
        (const __attribute__((address_space(1))) void*)(csrc + (size_t)h * 4096),
        (__attribute__((address_space(3))) void*)(&cb[buf][0]), 4, 0, 0);
  };

  f32x4 acc[4][4];
#pragma unroll
  for (int a = 0; a < 4; ++a)
#pragma unroll
    for (int b = 0; b < 4; ++b) acc[a][b] = f32x4{0.f, 0.f, 0.f, 0.f};

  // Prologue: fill 3 of the 4 buffers; wait for half 0 (keep 6 in flight).
  stage(0);
  stage(1);
  stage(2);
  asm volatile("s_waitcnt vmcnt(6)" ::: "memory");
  __builtin_amdgcn_s_barrier();

  const unsigned q4 = (unsigned)(lane >> 4) * 4u;

  for (int H = 0; H < NH; ++H) {
    if (H + 3 < NH) stage(H + 3);  // into buf (H+3)&3 == (H-1)&3, freed by barrier

    const uint4* wbh = &wb[H & 3][(unsigned)wn * 256u + (unsigned)lane];
    short8 bf[4];
#pragma unroll
    for (int nf = 0; nf < 4; ++nf) bf[nf] = *(const short8*)(wbh + nf * 64);

    // 4 channel-pairs for this wave's row groups: one ds_read_b64.
    uint2 chd = *(const uint2*)((const char*)&cb[H & 3][0] +
                                (unsigned)(lane & 15) * 16u + (unsigned)wm * 8u);
    unsigned short hh[4];
    hh[0] = (unsigned short)(chd.x & 0xffffu);
    hh[1] = (unsigned short)(chd.x >> 16);
    hh[2] = (unsigned short)(chd.y & 0xffffu);
    hh[3] = (unsigned short)(chd.y >> 16);

    __builtin_amdgcn_s_setprio(1);
#pragma unroll
    for (int mi = 0; mi < 4; ++mi) {
      unsigned pk = hh[mi];
      unsigned r0 = (pk & 15u) - q4;
      unsigned r1 = ((pk >> 8) & 15u) - q4;
      unsigned long long p0 = (r0 < 4u) ? (0x3F80ull << ((r0 & 3u) << 4)) : 0ull;
      unsigned long long p1 = (r1 < 4u) ? (0x3F80ull << ((r1 & 3u) << 4)) : 0ull;
      union { short8 v; unsigned u[4]; } af;
      af.u[0] = (unsigned)p0;
      af.u[1] = (unsigned)(p0 >> 32);
      af.u[2] = (unsigned)p1;
      af.u[3] = (unsigned)(p1 >> 32);
#pragma unroll
      for (int nf = 0; nf < 4; ++nf)
        acc[mi][nf] = __builtin_amdgcn_mfma_f32_16x16x32_bf16(
            af.v, bf[nf], acc[mi][nf], 0, 0, 0);
    }
    __builtin_amdgcn_s_setprio(0);

    // Counted waits: keep next halves' loads in flight, never drain to 0
    // until the tail. 6 = 2 future halves x 3 loads.
    if (H < NH - 3)
      asm volatile("s_waitcnt vmcnt(6)" ::: "memory");
    else if (H == NH - 3)
      asm volatile("s_waitcnt vmcnt(3)" ::: "memory");
    else
      asm volatile("s_waitcnt vmcnt(0)" ::: "memory");
    __builtin_amdgcn_s_barrier();
  }

  const int row0 = (int)mBlk * 128 + wm * 64;
  const int col0 = (int)nBlk * 128 + wn * 64;
  const int rsub = (lane >> 4) * 4;
  const int csub = lane & 15;
#pragma unroll
  for (int mi = 0; mi < 4; ++mi)
#pragma unroll
    for (int nf = 0; nf < 4; ++nf) {
      int r = row0 + mi * 16 + rsub;
      int c = col0 + nf * 16 + csub;
#pragma unroll
      for (int j = 0; j < 4; ++j)
        unsafeAtomicAdd(&out[(size_t)(r + j) * 2048 + c], acc[mi][nf][j]);
    }
}

// ---------------------------------------------------------------------------
// Fallback (ws too small): direct gather row-sum, one block per sample.
// ---------------------------------------------------------------------------
__global__ __launch_bounds__(256) void k_direct(const float* __restrict__ x,
                                                const int* __restrict__ anc,
                                                const float* __restrict__ W,
                                                float* __restrict__ out) {
  __shared__ unsigned rowoff[1024];
  const int b = blockIdx.x;
  const bool is64 = anchors_is_i64(anc);
  for (int d = threadIdx.x; d < 1024; d += 256) {
    unsigned ch = 0;
#pragma unroll
    for (int i = 0; i < 4; ++i) {
      int a = ld_anchor(anc, d * 4 + i, is64);
      ch |= (x[(size_t)b * 2048 + a] > 0.0f ? 1u : 0u) << i;
    }
    rowoff[d] = (unsigned)(d * 16 + ch) * 2048u;
  }
  __syncthreads();
  f32x4 a0 = {0.f, 0.f, 0.f, 0.f}, a1 = {0.f, 0.f, 0.f, 0.f};
  const int o0 = threadIdx.x * 4, o1 = 1024 + threadIdx.x * 4;
  for (int d = 0; d < 1024; ++d) {
    unsigned ro = rowoff[d];
    a0 += *(const f32x4*)(W + ro + o0);
    a1 += *(const f32x4*)(W + ro + o1);
  }
  *(f32x4*)(out + (size_t)b * 2048 + o0) = a0;
  *(f32x4*)(out + (size_t)b * 2048 + o1) = a1;
}

// ---------------------------------------------------------------------------
extern "C" void kernel_launch(void* const* d_in, const int* in_sizes, int n_in,
                              void* d_out, int out_size, void* d_ws, size_t ws_size,
                              hipStream_t stream) {
  const float* x = (const float*)d_in[0];
  const int* anc = (const int*)d_in[1];
  const float* W = (const float*)d_in[2];
  float* out = (float*)d_out;

  const size_t CHP_BYTES = 2ull * 1024 * 1024;  // 512 x 2048 u16
  const size_t WF_BYTES = 64ull * 1024 * 1024;  // 4M x 16 B
  const size_t BASE = CHP_BYTES + WF_BYTES;     // 66 MiB

  if (ws_size < BASE) {
    k_direct<<<2048, 256, 0, stream>>>(x, anc, W, out);
    return;
  }

  unsigned short* chT = (unsigned short*)d_ws;
  uint4* wf = (uint4*)((char*)d_ws + CHP_BYTES);

  hipMemsetAsync(d_out, 0, (size_t)out_size * sizeof(float), stream);
  k_channels<<<dim3(8, 512), 256, 0, stream>>>(x, anc, chT);
  k_wfrag<<<16384, 256, 0, stream>>>(W, wf);
  k_gemm<<<1024, 256, 0, stream>>>(wf, chT, out);
}

// Round 6
// 182.843 us; speedup vs baseline: 1.3356x; 1.3356x over previous
//
#include <hip/hip_runtime.h>
#include <hip/hip_bf16.h>

// LUTLayerBasic: out[b] = sum_d W[d*16 + ch(b,d)], ch = 4 sign bits of gathered x.
// R6 = R5 with the W-staging address bug fixed: wf chunks for consecutive K32
// steps are NOT contiguous (stride 8192 chunks per kt at fixed nBlk); stage
// each kt from its own base pointer.
//  - R1 skeleton: static ping-pong dbuf, global_load_lds staging, one
//    __syncthreads per barrier.
//  - LDS LUT removed: A one-hot built arithmetically (R3/R4-verified math).
//  - Channels staged in LDS, one ds_read_b64 per wave-step (R4-verified layout).
//  - BK=64 per barrier (2 K32 halves) -> half the barrier drains; 32.5 KiB LDS.
//  - Prep: x transposed+bitpacked (k_bits) so channel gather is coalesced.
//  - Split-K KP=4 via HW f32 atomics into memset-zeroed out.
//
// Dims: B=2048, N_IN=2048, D=1024, A=4, O=2048, C=16, K=N_LUT=16384.

typedef __attribute__((ext_vector_type(8))) short short8;
typedef __attribute__((ext_vector_type(4))) float f32x4;

__device__ __forceinline__ bool anchors_is_i64(const int* a) {
  int v = 0;
#pragma unroll
  for (int i = 0; i < 32; ++i) v |= a[2 * i + 1];
  return v == 0;
}

__device__ __forceinline__ int ld_anchor(const int* a, int i, bool is64) {
  return is64 ? a[2 * i] : a[i];
}

__device__ __forceinline__ unsigned f2bf(float f) {  // RNE f32 -> bf16
  unsigned u = __float_as_uint(f);
  return ((u + 0x7fffu + ((u >> 16) & 1u)) >> 16) & 0xffffu;
}

// ---------------------------------------------------------------------------
// Kernel 0: transpose + bitpack. xbT[n][s] = (x[s][n] > 0) as byte.
// ---------------------------------------------------------------------------
__global__ __launch_bounds__(256) void k_bits(const float* __restrict__ x,
                                              unsigned char* __restrict__ xbT) {
  __shared__ unsigned char t[64][65];
  const int tid = threadIdx.x;
  const int tr = blockIdx.x * 64, tc = blockIdx.y * 64;
  const int c = tid & 63, r0 = tid >> 6;
#pragma unroll
  for (int j = 0; j < 16; ++j) {
    int r = r0 + j * 4;
    t[c][r] = x[(size_t)(tr + r) * 2048 + tc + c] > 0.0f ? 1 : 0;
  }
  __syncthreads();
#pragma unroll
  for (int j = 0; j < 16; ++j) {
    int n = r0 + j * 4;
    xbT[(size_t)(tc + n) * 2048 + tr + c] = t[n][c];
  }
}

// ---------------------------------------------------------------------------
// Kernel 1: packed channels from bitplane, TRANSPOSED layout:
// for s = g*128 + m8*16 + r: chT[t*2048 + g*128 + r*8 + m8] = ch(s,2t)|ch(s,2t+1)<<8
// ---------------------------------------------------------------------------
__global__ __launch_bounds__(256) void k_channels2(const unsigned char* __restrict__ xbT,
                                                   const int* __restrict__ anc,
                                                   unsigned short* __restrict__ chT) {
  const int s = blockIdx.x * 256 + threadIdx.x;  // gridDim.x = 8
  const int t = blockIdx.y;                      // [0, 512)
  const bool is64 = anchors_is_i64(anc);
  unsigned ch0 = 0, ch1 = 0;
#pragma unroll
  for (int i = 0; i < 4; ++i) {
    int a0 = ld_anchor(anc, (2 * t) * 4 + i, is64);
    int a1 = ld_anchor(anc, (2 * t + 1) * 4 + i, is64);
    ch0 |= (unsigned)xbT[(size_t)a0 * 2048 + s] << i;
    ch1 |= (unsigned)xbT[(size_t)a1 * 2048 + s] << i;
  }
  const int g = s >> 7, m8 = (s >> 4) & 7, r = s & 15;
  chT[(size_t)t * 2048 + g * 128 + r * 8 + m8] =
      (unsigned short)(ch0 | (ch1 << 8));
}

// Fallback channels (no xbT scratch): direct strided gather from x.
__global__ __launch_bounds__(256) void k_channels(const float* __restrict__ x,
                                                  const int* __restrict__ anc,
                                                  unsigned short* __restrict__ chT) {
  const int s = blockIdx.x * 256 + threadIdx.x;
  const int t = blockIdx.y;
  const bool is64 = anchors_is_i64(anc);
  unsigned ch0 = 0, ch1 = 0;
#pragma unroll
  for (int i = 0; i < 4; ++i) {
    int a0 = ld_anchor(anc, (2 * t) * 4 + i, is64);
    int a1 = ld_anchor(anc, (2 * t + 1) * 4 + i, is64);
    ch0 |= (x[(size_t)s * 2048 + a0] > 0.0f ? 1u : 0u) << i;
    ch1 |= (x[(size_t)s * 2048 + a1] > 0.0f ? 1u : 0u) << i;
  }
  const int g = s >> 7, m8 = (s >> 4) & 7, r = s & 15;
  chT[(size_t)t * 2048 + g * 128 + r * 8 + m8] =
      (unsigned short)(ch0 | (ch1 << 8));
}

// ---------------------------------------------------------------------------
// Kernel 2: W (f32 [16384][2048]) -> bf16 fragment-linear chunks:
//   chunk ((kt*128 + nc)*64 + l) is 16 B holding
//   W[kt*32 + kmap(l>>4, j)][nc*16 + (l&15)], kmap(q,j)=q*4+(j&3)+16*(j>>2).
// ---------------------------------------------------------------------------
__global__ __launch_bounds__(256) void k_wfrag(const float* __restrict__ W,
                                               uint4* __restrict__ wf) {
  const unsigned flat = blockIdx.x * 256 + threadIdx.x;  // [0, 4194304)
  const unsigned l = flat & 63u, nc = (flat >> 6) & 127u, kt = flat >> 13;
  const unsigned q = l >> 4, col = nc * 16 + (l & 15);
  unsigned hs[8];
#pragma unroll
  for (int j = 0; j < 8; ++j) {
    unsigned k = kt * 32 + q * 4 + (j & 3) + ((j >> 2) << 4);
    hs[j] = f2bf(W[(size_t)k * 2048 + col]);
  }
  uint4 o;
  o.x = hs[0] | (hs[1] << 16);
  o.y = hs[2] | (hs[3] << 16);
  o.z = hs[4] | (hs[5] << 16);
  o.w = hs[6] | (hs[7] << 16);
  wf[flat] = o;
}

// ---------------------------------------------------------------------------
// Kernel 3: one-hot GEMM. Tile 128x128, 4 waves 2x2, wave 64x64, BK=64 per
// barrier (2 K32 halves, staged from separate kt base pointers), static
// ping-pong dbuf, KP=4 via atomics. Grid 1024.
// ---------------------------------------------------------------------------
__global__ __launch_bounds__(256, 4) void k_gemm(const uint4* __restrict__ wf,
                                                 const unsigned short* __restrict__ chT,
                                                 float* __restrict__ out) {
  constexpr int NB = 64;                  // BK=64 steps per kp slice (KP=4)
  __shared__ uint4 wb[2][1024];           // 2 x 16 KiB W tiles
  __shared__ unsigned short cb[2][256];   // 2 x 512 B channel tiles (2 kt's)

  const int tid = threadIdx.x, lane = tid & 63;
  const int w = tid >> 6, wm = w >> 1, wn = w & 1;

  // XCD-grouping swizzle (1024 = 8 XCD x 128): all 16 mBlk's of one (nBlk,kp)
  // W-panel on one XCD -> 2 MiB panel L2-resident.
  const unsigned orig = blockIdx.x;
  const unsigned xcd = orig & 7u, slot = orig >> 3;
  const unsigned pl = slot >> 4, mBlk = slot & 15u;
  const unsigned panel = xcd * 8u + pl;  // [0, 64)
  const unsigned nBlk = panel & 15u, kp = panel >> 4;
  const int kt0 = (int)kp * NB * 2;      // K32-step origin

  const uint4* wsrc = wf + ((size_t)(unsigned)kt0 * 128u + nBlk * 8u) * 64u;
  const char* csrc = (const char*)(chT + (size_t)(unsigned)kt0 * 2048u + mBlk * 128u) +
                     (unsigned)lane * 4u;

  // Stage one BK=64 tile = two K32 steps. wf chunks for kt and kt+1 at fixed
  // nBlk are 8192 chunks apart -> two base pointers (R5 bug fix).
  auto stage = [&](int bs, int buf) {
    const uint4* ws0 = wsrc + (size_t)(2 * bs) * 8192;
    const uint4* ws1 = ws0 + 8192;
#pragma unroll
    for (int t2 = 0; t2 < 2; ++t2) {
      __builtin_amdgcn_global_load_lds(
          (const __attribute__((address_space(1))) void*)(ws0 + t2 * 256 + tid),
          (__attribute__((address_space(3))) void*)(&wb[buf][t2 * 256 + w * 64]),
          16, 0, 0);
    }
#pragma unroll
    for (int t2 = 0; t2 < 2; ++t2) {
      __builtin_amdgcn_global_load_lds(
          (const __attribute__((address_space(1))) void*)(ws1 + t2 * 256 + tid),
          (__attribute__((address_space(3))) void*)(&wb[buf][512 + t2 * 256 + w * 64]),
          16, 0, 0);
    }
    if (w == 0) {
      __builtin_amdgcn_global_load_lds(
          (const __attribute__((address_space(1))) void*)(csrc + (size_t)bs * 8192),
          (__attribute__((address_space(3))) void*)(&cb[buf][0]), 4, 0, 0);
      __builtin_amdgcn_global_load_lds(
          (const __attribute__((address_space(1))) void*)(csrc + (size_t)bs * 8192 + 4096),
          (__attribute__((address_space(3))) void*)(&cb[buf][128]), 4, 0, 0);
    }
  };

  f32x4 acc[4][4];
#pragma unroll
  for (int a = 0; a < 4; ++a)
#pragma unroll
    for (int b = 0; b < 4; ++b) acc[a][b] = f32x4{0.f, 0.f, 0.f, 0.f};

  const unsigned q4 = (unsigned)(lane >> 4) * 4u;
  const unsigned choff = (unsigned)(lane & 15) * 16u + (unsigned)wm * 8u;

  // One K32 half-step from buffer `buf`, half h (0 or 1).
#define HALF(buf, h)                                                          \
  {                                                                           \
    const uint4* wbh = &wb[buf][(h)*512u + (unsigned)wn * 256u + (unsigned)lane]; \
    short8 bfr[4];                                                            \
    _Pragma("unroll") for (int nf = 0; nf < 4; ++nf)                          \
        bfr[nf] = *(const short8*)(wbh + nf * 64);                            \
    uint2 chd = *(const uint2*)((const char*)&cb[buf][(h)*128u] + choff);     \
    unsigned short hh[4];                                                     \
    hh[0] = (unsigned short)(chd.x & 0xffffu);                                \
    hh[1] = (unsigned short)(chd.x >> 16);                                    \
    hh[2] = (unsigned short)(chd.y & 0xffffu);                                \
    hh[3] = (unsigned short)(chd.y >> 16);                                    \
    _Pragma("unroll") for (int mi = 0; mi < 4; ++mi) {                        \
      unsigned pk = hh[mi];                                                   \
      unsigned r0 = (pk & 15u) - q4;                                          \
      unsigned r1 = ((pk >> 8) & 15u) - q4;                                   \
      unsigned long long p0 = (r0 < 4u) ? (0x3F80ull << (r0 << 4)) : 0ull;    \
      unsigned long long p1 = (r1 < 4u) ? (0x3F80ull << (r1 << 4)) : 0ull;    \
      union { short8 v; unsigned u[4]; } af;                                  \
      af.u[0] = (unsigned)p0; af.u[1] = (unsigned)(p0 >> 32);                 \
      af.u[2] = (unsigned)p1; af.u[3] = (unsigned)(p1 >> 32);                 \
      _Pragma("unroll") for (int nf = 0; nf < 4; ++nf)                        \
        acc[mi][nf] = __builtin_amdgcn_mfma_f32_16x16x32_bf16(                \
            af.v, bfr[nf], acc[mi][nf], 0, 0, 0);                             \
    }                                                                         \
  }

  stage(0, 0);
  __syncthreads();

  for (int p = 0; p < NB; p += 2) {
    stage(p + 1, 1);
    HALF(0, 0)
    HALF(0, 1)
    __syncthreads();
    if (p + 2 < NB) stage(p + 2, 0);
    HALF(1, 0)
    HALF(1, 1)
    __syncthreads();
  }
#undef HALF

  const int row0 = (int)mBlk * 128 + wm * 64;
  const int col0 = (int)nBlk * 128 + wn * 64;
  const int rsub = (lane >> 4) * 4;
  const int csub = lane & 15;
#pragma unroll
  for (int mi = 0; mi < 4; ++mi)
#pragma unroll
    for (int nf = 0; nf < 4; ++nf) {
      int r = row0 + mi * 16 + rsub;
      int c = col0 + nf * 16 + csub;
#pragma unroll
      for (int j = 0; j < 4; ++j)
        unsafeAtomicAdd(&out[(size_t)(r + j) * 2048 + c], acc[mi][nf][j]);
    }
}

// ---------------------------------------------------------------------------
// Fallback (ws too small): direct gather row-sum, one block per sample.
// ---------------------------------------------------------------------------
__global__ __launch_bounds__(256) void k_direct(const float* __restrict__ x,
                                                const int* __restrict__ anc,
                                                const float* __restrict__ W,
                                                float* __restrict__ out) {
  __shared__ unsigned rowoff[1024];
  const int b = blockIdx.x;
  const bool is64 = anchors_is_i64(anc);
  for (int d = threadIdx.x; d < 1024; d += 256) {
    unsigned ch = 0;
#pragma unroll
    for (int i = 0; i < 4; ++i) {
      int a = ld_anchor(anc, d * 4 + i, is64);
      ch |= (x[(size_t)b * 2048 + a] > 0.0f ? 1u : 0u) << i;
    }
    rowoff[d] = (unsigned)(d * 16 + ch) * 2048u;
  }
  __syncthreads();
  f32x4 a0 = {0.f, 0.f, 0.f, 0.f}, a1 = {0.f, 0.f, 0.f, 0.f};
  const int o0 = threadIdx.x * 4, o1 = 1024 + threadIdx.x * 4;
  for (int d = 0; d < 1024; ++d) {
    unsigned ro = rowoff[d];
    a0 += *(const f32x4*)(W + ro + o0);
    a1 += *(const f32x4*)(W + ro + o1);
  }
  *(f32x4*)(out + (size_t)b * 2048 + o0) = a0;
  *(f32x4*)(out + (size_t)b * 2048 + o1) = a1;
}

// ---------------------------------------------------------------------------
extern "C" void kernel_launch(void* const* d_in, const int* in_sizes, int n_in,
                              void* d_out, int out_size, void* d_ws, size_t ws_size,
                              hipStream_t stream) {
  const float* x = (const float*)d_in[0];
  const int* anc = (const int*)d_in[1];
  const float* W = (const float*)d_in[2];
  float* out = (float*)d_out;

  const size_t CHP_BYTES = 2ull * 1024 * 1024;   // chT: 512 x 2048 u16
  const size_t WF_BYTES = 64ull * 1024 * 1024;   // wf: 4M x 16 B
  const size_t BASE = CHP_BYTES + WF_BYTES;      // 66 MiB
  const size_t XBT_BYTES = 4ull * 1024 * 1024;   // xbT: 2048 x 2048 u8

  if (ws_size < BASE) {
    k_direct<<<2048, 256, 0, stream>>>(x, anc, W, out);
    return;
  }

  unsigned short* chT = (unsigned short*)d_ws;
  uint4* wf = (uint4*)((char*)d_ws + CHP_BYTES);

  hipMemsetAsync(d_out, 0, (size_t)out_size * sizeof(float), stream);

  if (ws_size >= BASE + XBT_BYTES) {
    unsigned char* xbT = (unsigned char*)((char*)d_ws + BASE);
    k_bits<<<dim3(32, 32), 256, 0, stream>>>(x, xbT);
    k_channels2<<<dim3(8, 512), 256, 0, stream>>>(xbT, anc, chT);
  } else {
    k_channels<<<dim3(8, 512), 256, 0, stream>>>(x, anc, chT);
  }
  k_wfrag<<<16384, 256, 0, stream>>>(W, wf);
  k_gemm<<<1024, 256, 0, stream>>>(wf, chT, out);
}

// Round 7
// 146.900 us; speedup vs baseline: 1.6624x; 1.2447x over previous
//
#include <hip/hip_runtime.h>
#include <hip/hip_bf16.h>

// LUTLayerBasic: out[b] = sum_d W[d*16 + ch(b,d)], ch = 4 sign bits of gathered x.
// R7: i8 MFMA (mfma_i32_32x32x32_i8). A one-hot is exact in i8; W quantized to
// round(W*127) (error << threshold). 2x MFMA rate + half the W bytes vs bf16.
// Wave grid 1x4 (wave = 128 rows x 32 cols): no redundant B-fragment reads.
// Skeleton = R1/R6-proven ping-pong dbuf + __syncthreads, BK=64 per barrier.
// k ordering per K32 tile: lane q=l>>5, byte j <-> k = q*16+j, i.e. each lane
// holds one detector's 16 channels; one-hot A = single 128-bit byte shift.
// W permuted identically (layout-invariance: any slot-consistent bijection).
//
// Dims: B=2048, N_IN=2048, D=1024, A=4, O=2048, C=16, K=N_LUT=16384.

typedef __attribute__((ext_vector_type(4))) int i32x4;
typedef __attribute__((ext_vector_type(16))) int i32x16;
typedef __attribute__((ext_vector_type(4))) float f32x4;

__device__ __forceinline__ bool anchors_is_i64(const int* a) {
  int v = 0;
#pragma unroll
  for (int i = 0; i < 32; ++i) v |= a[2 * i + 1];
  return v == 0;
}

__device__ __forceinline__ int ld_anchor(const int* a, int i, bool is64) {
  return is64 ? a[2 * i] : a[i];
}

// One-hot A fragment: 16 bytes, byte[ch] = 1 (ch in [0,16)).
__device__ __forceinline__ i32x4 mkA(unsigned ch) {
  unsigned long long v = 1ull << ((ch << 3) & 63u);  // wraps for ch>=8
  union { unsigned long long q[2]; i32x4 v4; } u;
  u.q[0] = (ch < 8u) ? v : 0ull;
  u.q[1] = (ch < 8u) ? 0ull : v;
  return u.v4;
}

// ---------------------------------------------------------------------------
// Kernel 0: transpose + bitpack. xbT[n][s] = (x[s][n] > 0) as byte.
// ---------------------------------------------------------------------------
__global__ __launch_bounds__(256) void k_bits(const float* __restrict__ x,
                                              unsigned char* __restrict__ xbT) {
  __shared__ unsigned char t[64][65];
  const int tid = threadIdx.x;
  const int tr = blockIdx.x * 64, tc = blockIdx.y * 64;
  const int c = tid & 63, r0 = tid >> 6;
#pragma unroll
  for (int j = 0; j < 16; ++j) {
    int r = r0 + j * 4;
    t[c][r] = x[(size_t)(tr + r) * 2048 + tc + c] > 0.0f ? 1 : 0;
  }
  __syncthreads();
#pragma unroll
  for (int j = 0; j < 16; ++j) {
    int n = r0 + j * 4;
    xbT[(size_t)(tc + n) * 2048 + tr + c] = t[n][c];
  }
}

// ---------------------------------------------------------------------------
// Kernel 1: channel quads. chQ[kq][s] = ch(s,4kq) | ch(s,4kq+1)<<8
//                                      | ch(s,4kq+2)<<16 | ch(s,4kq+3)<<24.
// ---------------------------------------------------------------------------
__global__ __launch_bounds__(256) void k_channels3(const unsigned char* __restrict__ xbT,
                                                   const int* __restrict__ anc,
                                                   unsigned* __restrict__ chQ) {
  const int s = blockIdx.x * 256 + threadIdx.x;  // gridDim.x = 8
  const int kq = blockIdx.y;                     // [0, 256)
  const bool is64 = anchors_is_i64(anc);
  unsigned word = 0;
#pragma unroll
  for (int di = 0; di < 4; ++di) {
    const int d = kq * 4 + di;
    unsigned ch = 0;
#pragma unroll
    for (int i = 0; i < 4; ++i) {
      int a = ld_anchor(anc, d * 4 + i, is64);
      ch |= (unsigned)xbT[(size_t)a * 2048 + s] << i;
    }
    word |= ch << (di * 8);
  }
  chQ[(size_t)kq * 2048 + s] = word;
}

// ---------------------------------------------------------------------------
// Kernel 2: W (f32 [16384][2048]) -> i8 fragment-linear chunks:
//   chunk c_idx = (kt*64 + nc)*64 + l  (1024 B = 64 lanes x 16 B), byte j:
//   Wq[(2kt + (l>>5))*16 + j][nc*32 + (l&31)],  Wq = round(W*127).
// ---------------------------------------------------------------------------
__global__ __launch_bounds__(256) void k_wfrag_i8(const float* __restrict__ W,
                                                  uint4* __restrict__ wfq) {
  const unsigned flat = blockIdx.x * 256 + threadIdx.x;  // [0, 2097152)
  const unsigned l = flat & 63u, nc = (flat >> 6) & 63u, kt = flat >> 12;
  const unsigned dd = 2u * kt + (l >> 5), col = nc * 32u + (l & 31u);
  const float* base = W + (size_t)(dd * 16u) * 2048u + col;
  unsigned wd[4];
#pragma unroll
  for (int wi = 0; wi < 4; ++wi) {
    unsigned v = 0;
#pragma unroll
    for (int bj = 0; bj < 4; ++bj) {
      float f = base[(size_t)(wi * 4 + bj) * 2048u];
      int q = (int)(f * 127.0f + 0.5f);
      q = q < 0 ? 0 : (q > 127 ? 127 : q);
      v |= (unsigned)q << (bj * 8);
    }
    wd[wi] = v;
  }
  uint4 o;
  o.x = wd[0]; o.y = wd[1]; o.z = wd[2]; o.w = wd[3];
  wfq[flat] = o;
}

// ---------------------------------------------------------------------------
// Kernel 3: one-hot i8 GEMM. Block 128x128, 4 waves 1x4 (wave = 128 rows x
// 32 cols, 4 row-frags x 1 col-frag), BK=64 per barrier (2 K32 tiles),
// ping-pong dbuf, KP=4 split-K via f32 atomics. Grid 1024.
// ---------------------------------------------------------------------------
__global__ __launch_bounds__(256, 4) void k_gemm(const uint4* __restrict__ wfq,
                                                 const unsigned* __restrict__ chQ,
                                                 float* __restrict__ out) {
  constexpr int NB = 64;              // BK64 steps per kp slice (KP=4)
  __shared__ uint4 wb[2][512];        // 2 x 8 KiB W tiles (2 K32-halves each)
  __shared__ unsigned cbw[2][128];    // 2 x 512 B channel-quad tiles

  const int tid = threadIdx.x, lane = tid & 63;
  const int w = tid >> 6;             // wave = column slice [0,4)
  const unsigned q = (unsigned)(lane >> 5), q8 = q << 3;

  // XCD-grouping swizzle (1024 = 8 XCD x 128): all 16 mBlk's of one (nBlk,kp)
  // W-panel (512 KB i8) on one XCD -> L2-resident.
  const unsigned orig = blockIdx.x;
  const unsigned xcd = orig & 7u, slot = orig >> 3;
  const unsigned pl = slot >> 4, mBlk = slot & 15u;
  const unsigned panel = xcd * 8u + pl;  // [0, 64)
  const unsigned nBlk = panel & 15u, kp = panel >> 4;

  const int ktBase = (int)kp * 2 * NB;   // K32-tile origin
  const int kqBase = (int)kp * NB;       // BK64 (channel-quad) origin

  const uint4* wsrc = wfq + ((size_t)(unsigned)ktBase * 64u + nBlk * 4u) * 64u;
  const unsigned* csrc = chQ + (size_t)(unsigned)kqBase * 2048u + mBlk * 128u;

  // Stage one BK64 tile: two K32 chunk-groups (4096 uint4 apart) + 512 B ch.
  auto stage = [&](int bs, int buf) {
    const uint4* sA = wsrc + (size_t)(2 * bs) * 4096 + tid;
    const uint4* sB = sA + 4096;
    __builtin_amdgcn_global_load_lds(
        (const __attribute__((address_space(1))) void*)sA,
        (__attribute__((address_space(3))) void*)(&wb[buf][w * 64]), 16, 0, 0);
    __builtin_amdgcn_global_load_lds(
        (const __attribute__((address_space(1))) void*)sB,
        (__attribute__((address_space(3))) void*)(&wb[buf][256 + w * 64]), 16, 0, 0);
    if (w == 0) {
      const unsigned* cs = csrc + (size_t)bs * 2048 + lane;
      __builtin_amdgcn_global_load_lds(
          (const __attribute__((address_space(1))) void*)cs,
          (__attribute__((address_space(3))) void*)(&cbw[buf][0]), 4, 0, 0);
      __builtin_amdgcn_global_load_lds(
          (const __attribute__((address_space(1))) void*)(cs + 64),
          (__attribute__((address_space(3))) void*)(&cbw[buf][64]), 4, 0, 0);
    }
  };

  i32x16 acc[4] = {};

#define MFMA_I8(a, b, c) __builtin_amdgcn_mfma_i32_32x32x32_i8((a), (b), (c), 0, 0, 0)

  // One BK64 step from buffer `buf`: 2 K32 halves x 4 row-frags.
#define COMPUTE(buf)                                                          \
  {                                                                           \
    const unsigned* cbp = &cbw[buf][lane & 31];                               \
    const unsigned cw0 = cbp[0], cw1 = cbp[32], cw2 = cbp[64], cw3 = cbp[96]; \
    const i32x4 b0 = *(const i32x4*)(&wb[buf][w * 64 + lane]);                \
    const i32x4 b1 = *(const i32x4*)(&wb[buf][256 + w * 64 + lane]);          \
    {                                                                         \
      const unsigned sh = q8;                                                 \
      acc[0] = MFMA_I8(mkA((cw0 >> sh) & 15u), b0, acc[0]);                   \
      acc[1] = MFMA_I8(mkA((cw1 >> sh) & 15u), b0, acc[1]);                   \
      acc[2] = MFMA_I8(mkA((cw2 >> sh) & 15u), b0, acc[2]);                   \
      acc[3] = MFMA_I8(mkA((cw3 >> sh) & 15u), b0, acc[3]);                   \
    }                                                                         \
    {                                                                         \
      const unsigned sh = 16u + q8;                                           \
      acc[0] = MFMA_I8(mkA((cw0 >> sh) & 15u), b1, acc[0]);                   \
      acc[1] = MFMA_I8(mkA((cw1 >> sh) & 15u), b1, acc[1]);                   \
      acc[2] = MFMA_I8(mkA((cw2 >> sh) & 15u), b1, acc[2]);                   \
      acc[3] = MFMA_I8(mkA((cw3 >> sh) & 15u), b1, acc[3]);                   \
    }                                                                         \
  }

  stage(0, 0);
  __syncthreads();

  for (int p = 0; p < NB; p += 2) {
    stage(p + 1, 1);
    COMPUTE(0)
    __syncthreads();
    if (p + 2 < NB) stage(p + 2, 0);
    COMPUTE(1)
    __syncthreads();
  }
#undef COMPUTE

  // Epilogue: C/D 32x32 layout col=lane&31, row=(reg&3)+8*(reg>>2)+4*q.
  const int c = (int)nBlk * 128 + w * 32 + (lane & 31);
  const float scale = 1.0f / 127.0f;
#pragma unroll
  for (int rf = 0; rf < 4; ++rf) {
    const int r0 = (int)mBlk * 128 + rf * 32 + (int)(q * 4u);
#pragma unroll
    for (int reg = 0; reg < 16; ++reg) {
      int r = r0 + (reg & 3) + 8 * (reg >> 2);
      unsafeAtomicAdd(&out[(size_t)r * 2048 + c], (float)acc[rf][reg] * scale);
    }
  }
}

// ---------------------------------------------------------------------------
// Fallback (ws too small): direct gather row-sum, one block per sample.
// ---------------------------------------------------------------------------
__global__ __launch_bounds__(256) void k_direct(const float* __restrict__ x,
                                                const int* __restrict__ anc,
                                                const float* __restrict__ W,
                                                float* __restrict__ out) {
  __shared__ unsigned rowoff[1024];
  const int b = blockIdx.x;
  const bool is64 = anchors_is_i64(anc);
  for (int d = threadIdx.x; d < 1024; d += 256) {
    unsigned ch = 0;
#pragma unroll
    for (int i = 0; i < 4; ++i) {
      int a = ld_anchor(anc, d * 4 + i, is64);
      ch |= (x[(size_t)b * 2048 + a] > 0.0f ? 1u : 0u) << i;
    }
    rowoff[d] = (unsigned)(d * 16 + ch) * 2048u;
  }
  __syncthreads();
  f32x4 a0 = {0.f, 0.f, 0.f, 0.f}, a1 = {0.f, 0.f, 0.f, 0.f};
  const int o0 = threadIdx.x * 4, o1 = 1024 + threadIdx.x * 4;
  for (int d = 0; d < 1024; ++d) {
    unsigned ro = rowoff[d];
    a0 += *(const f32x4*)(W + ro + o0);
    a1 += *(const f32x4*)(W + ro + o1);
  }
  *(f32x4*)(out + (size_t)b * 2048 + o0) = a0;
  *(f32x4*)(out + (size_t)b * 2048 + o1) = a1;
}

// ---------------------------------------------------------------------------
extern "C" void kernel_launch(void* const* d_in, const int* in_sizes, int n_in,
                              void* d_out, int out_size, void* d_ws, size_t ws_size,
                              hipStream_t stream) {
  const float* x = (const float*)d_in[0];
  const int* anc = (const int*)d_in[1];
  const float* W = (const float*)d_in[2];
  float* out = (float*)d_out;

  const size_t CHQ_BYTES = 2ull * 1024 * 1024;   // chQ: 256 x 2048 u32
  const size_t WFQ_BYTES = 32ull * 1024 * 1024;  // wfq: 2M x 16 B (i8)
  const size_t XBT_BYTES = 4ull * 1024 * 1024;   // xbT: 2048 x 2048 u8
  const size_t BASE = CHQ_BYTES + WFQ_BYTES + XBT_BYTES;  // 38 MiB

  if (ws_size < BASE) {
    k_direct<<<2048, 256, 0, stream>>>(x, anc, W, out);
    return;
  }

  unsigned* chQ = (unsigned*)d_ws;
  uint4* wfq = (uint4*)((char*)d_ws + CHQ_BYTES);
  unsigned char* xbT = (unsigned char*)((char*)d_ws + CHQ_BYTES + WFQ_BYTES);

  hipMemsetAsync(d_out, 0, (size_t)out_size * sizeof(float), stream);
  k_bits<<<dim3(32, 32), 256, 0, stream>>>(x, xbT);
  k_channels3<<<dim3(8, 256), 256, 0, stream>>>(xbT, anc, chQ);
  k_wfrag_i8<<<8192, 256, 0, stream>>>(W, wfq);
  k_gemm<<<1024, 256, 0, stream>>>(wfq, chQ, out);
}

// Round 8
// 133.236 us; speedup vs baseline: 1.8329x; 1.1026x over previous
//
#include <hip/hip_runtime.h>
#include <hip/hip_bf16.h>

// LUTLayerBasic: out[b] = sum_d W[d*16 + ch(b,d)], ch = 4 sign bits of gathered x.
// R8: i8 MFMA, ZERO-LDS streaming GEMM. Each wave owns a 128x32 output slice
// (1x4 wave grid -> no inter-wave sharing), B fragments stream global->reg
// from the L2-resident pre-permuted i8 W panel, channels arrive as one
// dwordx4 per step. No barriers / no LDS in the K-loop; register prefetch
// distance 1; setprio around the MFMA cluster.
// A one-hot built arithmetically (R7-verified i8 layout: lane l, byte j <->
// k=(l>>5)*16+j, row=l&31); W permuted identically; split-K KP=4 via atomics.
//
// Dims: B=2048, N_IN=2048, D=1024, A=4, O=2048, C=16, K=N_LUT=16384.

typedef __attribute__((ext_vector_type(4))) int i32x4;
typedef __attribute__((ext_vector_type(16))) int i32x16;
typedef __attribute__((ext_vector_type(4))) float f32x4;

__device__ __forceinline__ bool anchors_is_i64(const int* a) {
  int v = 0;
#pragma unroll
  for (int i = 0; i < 32; ++i) v |= a[2 * i + 1];
  return v == 0;
}

__device__ __forceinline__ int ld_anchor(const int* a, int i, bool is64) {
  return is64 ? a[2 * i] : a[i];
}

// One-hot A fragment: 16 bytes, byte[ch] = 1 (ch in [0,16)). R7-verified.
__device__ __forceinline__ i32x4 mkA(unsigned ch) {
  unsigned long long v = 1ull << ((ch << 3) & 63u);
  union { unsigned long long q[2]; i32x4 v4; } u;
  u.q[0] = (ch < 8u) ? v : 0ull;
  u.q[1] = (ch < 8u) ? 0ull : v;
  return u.v4;
}

// ---------------------------------------------------------------------------
// Kernel 0: transpose + bitpack. xbT[n][s] = (x[s][n] > 0) as byte.
// ---------------------------------------------------------------------------
__global__ __launch_bounds__(256) void k_bits(const float* __restrict__ x,
                                              unsigned char* __restrict__ xbT) {
  __shared__ unsigned char t[64][65];
  const int tid = threadIdx.x;
  const int tr = blockIdx.x * 64, tc = blockIdx.y * 64;
  const int c = tid & 63, r0 = tid >> 6;
#pragma unroll
  for (int j = 0; j < 16; ++j) {
    int r = r0 + j * 4;
    t[c][r] = x[(size_t)(tr + r) * 2048 + tc + c] > 0.0f ? 1 : 0;
  }
  __syncthreads();
#pragma unroll
  for (int j = 0; j < 16; ++j) {
    int n = r0 + j * 4;
    xbT[(size_t)(tc + n) * 2048 + tr + c] = t[n][c];
  }
}

// ---------------------------------------------------------------------------
// Kernel 1: channel quads in GEMM-register layout. For sample s decomposed as
// s = g*128 + rf*32 + l (g row-group, rf row-frag, l lane):
//   chR[((kq*16 + g)*32 + l) * 4 + rf] = ch(s,4kq..4kq+3) packed bytes.
// One uint4 per (kq, g, l) holds all 4 row-frag words -> 1 dwordx4 in GEMM.
// ---------------------------------------------------------------------------
__global__ __launch_bounds__(256) void k_channels3(const unsigned char* __restrict__ xbT,
                                                   const int* __restrict__ anc,
                                                   unsigned* __restrict__ chR) {
  const int s = blockIdx.x * 256 + threadIdx.x;  // gridDim.x = 8
  const int kq = blockIdx.y;                     // [0, 256)
  const bool is64 = anchors_is_i64(anc);
  unsigned word = 0;
#pragma unroll
  for (int di = 0; di < 4; ++di) {
    const int d = kq * 4 + di;
    unsigned ch = 0;
#pragma unroll
    for (int i = 0; i < 4; ++i) {
      int a = ld_anchor(anc, d * 4 + i, is64);
      ch |= (unsigned)xbT[(size_t)a * 2048 + s] << i;
    }
    word |= ch << (di * 8);
  }
  const int g = s >> 7, rf = (s >> 5) & 3, l = s & 31;
  chR[(((size_t)kq * 16 + g) * 32 + l) * 4 + rf] = word;
}

// ---------------------------------------------------------------------------
// Kernel 2: W (f32 [16384][2048]) -> i8 fragment-linear chunks:
//   chunk c_idx = (kt*64 + nc)*64 + l  (16 B), byte j:
//   Wq[(2kt + (l>>5))*16 + j][nc*32 + (l&31)],  Wq = round(W*127).
// ---------------------------------------------------------------------------
__global__ __launch_bounds__(256) void k_wfrag_i8(const float* __restrict__ W,
                                                  uint4* __restrict__ wfq) {
  const unsigned flat = blockIdx.x * 256 + threadIdx.x;  // [0, 2097152)
  const unsigned l = flat & 63u, nc = (flat >> 6) & 63u, kt = flat >> 12;
  const unsigned dd = 2u * kt + (l >> 5), col = nc * 32u + (l & 31u);
  const float* base = W + (size_t)(dd * 16u) * 2048u + col;
  unsigned wd[4];
#pragma unroll
  for (int wi = 0; wi < 4; ++wi) {
    unsigned v = 0;
#pragma unroll
    for (int bj = 0; bj < 4; ++bj) {
      float f = base[(size_t)(wi * 4 + bj) * 2048u];
      int q = (int)(f * 127.0f + 0.5f);
      q = q < 0 ? 0 : (q > 127 ? 127 : q);
      v |= (unsigned)q << (bj * 8);
    }
    wd[wi] = v;
  }
  uint4 o;
  o.x = wd[0]; o.y = wd[1]; o.z = wd[2]; o.w = wd[3];
  wfq[flat] = o;
}

// ---------------------------------------------------------------------------
// Kernel 3: zero-LDS streaming i8 GEMM. Block 128x128, 4 waves 1x4 (wave =
// 128 rows x 32 cols), BK=64 per iteration, register prefetch distance 1,
// no barriers, KP=4 split-K via f32 atomics. Grid 1024.
// ---------------------------------------------------------------------------
__global__ __launch_bounds__(256, 4) void k_gemm(const uint4* __restrict__ wfq,
                                                 const uint4* __restrict__ chR,
                                                 float* __restrict__ out) {
  constexpr int NB = 64;  // BK64 steps per kp slice (KP=4)

  const int tid = threadIdx.x, lane = tid & 63;
  const int w = tid >> 6;  // wave = column slice [0,4)
  const unsigned q = (unsigned)(lane >> 5), q8 = q << 3;

  // XCD-grouping swizzle (1024 = 8 XCD x 128): all 16 mBlk's of one (nBlk,kp)
  // W-panel (512 KB i8) on one XCD -> L2-resident.
  const unsigned orig = blockIdx.x;
  const unsigned xcd = orig & 7u, slot = orig >> 3;
  const unsigned pl = slot >> 4, mBlk = slot & 15u;
  const unsigned panel = xcd * 8u + pl;  // [0, 64)
  const unsigned nBlk = panel & 15u, kp = panel >> 4;

  const unsigned ktBase = kp * 2u * NB;  // K32-tile origin
  const unsigned kqBase = kp * NB;       // BK64 (channel-quad) origin

  // W fragment pointer: chunk (kt*64 + nc)*64 + lane, nc = nBlk*4 + w.
  // BK64 step stride = 2 kt = 8192 uint4; second K32 half at +4096.
  const uint4* wp = wfq + ((size_t)ktBase * 64u + (nBlk * 4u + (unsigned)w)) * 64u + lane;
  // Channel pointer: one uint4 per (kq, g=mBlk, lane&31); step stride 512.
  const uint4* cp = chR + ((size_t)kqBase * 16u + mBlk) * 32u + (lane & 31);

  i32x16 acc[4] = {};

#define MFMA_I8(a, b, c) __builtin_amdgcn_mfma_i32_32x32x32_i8((a), (b), (c), 0, 0, 0)

  uint4 b0 = wp[0];
  uint4 b1 = wp[4096];
  uint4 cq = cp[0];

  for (int bs = 0; bs < NB; ++bs) {
    const int nxt = (bs + 1 < NB) ? bs + 1 : bs;  // tail: redundant reload
    uint4 nb0 = wp[(size_t)nxt * 8192];
    uint4 nb1 = wp[(size_t)nxt * 8192 + 4096];
    uint4 ncq = cp[(size_t)nxt * 512];

    const i32x4 vb0 = *(const i32x4*)&b0;
    const i32x4 vb1 = *(const i32x4*)&b1;

    __builtin_amdgcn_s_setprio(1);
    acc[0] = MFMA_I8(mkA((cq.x >> q8) & 15u), vb0, acc[0]);
    acc[1] = MFMA_I8(mkA((cq.y >> q8) & 15u), vb0, acc[1]);
    acc[2] = MFMA_I8(mkA((cq.z >> q8) & 15u), vb0, acc[2]);
    acc[3] = MFMA_I8(mkA((cq.w >> q8) & 15u), vb0, acc[3]);
    acc[0] = MFMA_I8(mkA((cq.x >> (16u + q8)) & 15u), vb1, acc[0]);
    acc[1] = MFMA_I8(mkA((cq.y >> (16u + q8)) & 15u), vb1, acc[1]);
    acc[2] = MFMA_I8(mkA((cq.z >> (16u + q8)) & 15u), vb1, acc[2]);
    acc[3] = MFMA_I8(mkA((cq.w >> (16u + q8)) & 15u), vb1, acc[3]);
    __builtin_amdgcn_s_setprio(0);

    b0 = nb0; b1 = nb1; cq = ncq;
  }

  // Epilogue: C/D 32x32 layout col=lane&31, row=(reg&3)+8*(reg>>2)+4*q.
  const int c = (int)nBlk * 128 + w * 32 + (lane & 31);
  const float scale = 1.0f / 127.0f;
#pragma unroll
  for (int rf = 0; rf < 4; ++rf) {
    const int r0 = (int)mBlk * 128 + rf * 32 + (int)(q * 4u);
#pragma unroll
    for (int reg = 0; reg < 16; ++reg) {
      int r = r0 + (reg & 3) + 8 * (reg >> 2);
      unsafeAtomicAdd(&out[(size_t)r * 2048 + c], (float)acc[rf][reg] * scale);
    }
  }
}

// ---------------------------------------------------------------------------
// Fallback (ws too small): direct gather row-sum, one block per sample.
// ---------------------------------------------------------------------------
__global__ __launch_bounds__(256) void k_direct(const float* __restrict__ x,
                                                const int* __restrict__ anc,
                                                const float* __restrict__ W,
                                                float* __restrict__ out) {
  __shared__ unsigned rowoff[1024];
  const int b = blockIdx.x;
  const bool is64 = anchors_is_i64(anc);
  for (int d = threadIdx.x; d < 1024; d += 256) {
    unsigned ch = 0;
#pragma unroll
    for (int i = 0; i < 4; ++i) {
      int a = ld_anchor(anc, d * 4 + i, is64);
      ch |= (x[(size_t)b * 2048 + a] > 0.0f ? 1u : 0u) << i;
    }
    rowoff[d] = (unsigned)(d * 16 + ch) * 2048u;
  }
  __syncthreads();
  f32x4 a0 = {0.f, 0.f, 0.f, 0.f}, a1 = {0.f, 0.f, 0.f, 0.f};
  const int o0 = threadIdx.x * 4, o1 = 1024 + threadIdx.x * 4;
  for (int d = 0; d < 1024; ++d) {
    unsigned ro = rowoff[d];
    a0 += *(const f32x4*)(W + ro + o0);
    a1 += *(const f32x4*)(W + ro + o1);
  }
  *(f32x4*)(out + (size_t)b * 2048 + o0) = a0;
  *(f32x4*)(out + (size_t)b * 2048 + o1) = a1;
}

// ---------------------------------------------------------------------------
extern "C" void kernel_launch(void* const* d_in, const int* in_sizes, int n_in,
                              void* d_out, int out_size, void* d_ws, size_t ws_size,
                              hipStream_t stream) {
  const float* x = (const float*)d_in[0];
  const int* anc = (const int*)d_in[1];
  const float* W = (const float*)d_in[2];
  float* out = (float*)d_out;

  const size_t CHR_BYTES = 2ull * 1024 * 1024;   // chR: 256 x 16 x 32 uint4
  const size_t WFQ_BYTES = 32ull * 1024 * 1024;  // wfq: 2M x 16 B (i8)
  const size_t XBT_BYTES = 4ull * 1024 * 1024;   // xbT: 2048 x 2048 u8
  const size_t BASE = CHR_BYTES + WFQ_BYTES + XBT_BYTES;  // 38 MiB

  if (ws_size < BASE) {
    k_direct<<<2048, 256, 0, stream>>>(x, anc, W, out);
    return;
  }

  unsigned* chR = (unsigned*)d_ws;
  uint4* wfq = (uint4*)((char*)d_ws + CHR_BYTES);
  unsigned char* xbT = (unsigned char*)((char*)d_ws + CHR_BYTES + WFQ_BYTES);

  hipMemsetAsync(d_out, 0, (size_t)out_size * sizeof(float), stream);
  k_bits<<<dim3(32, 32), 256, 0, stream>>>(x, xbT);
  k_channels3<<<dim3(8, 256), 256, 0, stream>>>(xbT, anc, chR);
  k_wfrag_i8<<<8192, 256, 0, stream>>>(W, wfq);
  k_gemm<<<1024, 256, 0, stream>>>(wfq, (const uint4*)chR, out);
}